// Round 4
// baseline (425.339 us; speedup 1.0000x reference)
//
#include <hip/hip_runtime.h>
#include <stdint.h>

#define N_NODES   50000
#define N_EDGES   400000
#define IN_FEATS  16
#define HIDDEN    32
#define K1        128      // EDGE_MLP_HID
#define NOUT      512      // IN_FEATS*HIDDEN
#define N_CLS     100000
#define TILE_E    64
#define N_TILES   (N_EDGES / TILE_E)   // 6250
#define GRID_F    256
#define CAP       40       // max degree slots (Poisson(8): P(deg>40) ~ 1e-15)

typedef float  f32x4  __attribute__((ext_vector_type(4)));
typedef __bf16 bf16x8 __attribute__((ext_vector_type(8)));

__device__ __forceinline__ unsigned short f32_bf16(float f) {
    union { float f; uint32_t u; } c; c.f = f;
    uint32_t r = c.u + 0x7fffu + ((c.u >> 16) & 1u);
    return (unsigned short)(r >> 16);
}

// ---- prep: W2 [128,512] -> W2T bf16 [512,128]; W1 [16,128] -> W1T bf16 [128,32] (K padded) ----
__global__ void prep_weights(const float* __restrict__ w2, const float* __restrict__ w1,
                             unsigned short* __restrict__ w2t, unsigned short* __restrict__ w1t) {
    int tid = blockIdx.x * 256 + threadIdx.x;
    if (tid < NOUT * K1) {
        int n = tid >> 7, k = tid & 127;
        w2t[n * 128 + k] = f32_bf16(w2[k * 512 + n]);
    } else {
        int t = tid - NOUT * K1;            // [0, 4096)
        int n = t >> 5, k = t & 31;
        w1t[n * 32 + k] = (k < 16) ? f32_bf16(w1[k * 128 + n]) : (unsigned short)0;
    }
}

__global__ void zero_int(int* __restrict__ p, int n) {
    int i = blockIdx.x * 256 + threadIdx.x;
    if (i < n) p[i] = 0;
}

// ---- bucket edges by dst: cursor[d] = degree, slots[d*CAP + j] = edge id ----
__global__ void build_slots(const int* __restrict__ dst, int* __restrict__ cursor,
                            int* __restrict__ slots) {
    int e = blockIdx.x * 256 + threadIdx.x;
    if (e >= N_EDGES) return;
    int d = dst[e];
    int pos = atomicAdd(&cursor[d], 1);
    if (pos < CAP) slots[d * CAP + pos] = e;
}

// ---- fused: edge MLP (MFMA, swapped operands, W2T fully LDS-resident) + per-edge matvec ----
// 512 threads = 8 waves: wc = wid&3 owns 128 output cols, eg = wid>>2 owns 32 edges.
// Writes msg[e][32] with plain stores (no global atomics).
__global__ __launch_bounds__(512) void fused_msg(
    const float* __restrict__ nf, const float* __restrict__ ef,
    const int* __restrict__ src,
    const unsigned short* __restrict__ w1t, const float* __restrict__ b1,
    const unsigned short* __restrict__ w2t, const float* __restrict__ b2,
    float* __restrict__ msg)
{
    __shared__ __align__(16) unsigned short sB[512 * 128];    // 128KB W2T, swizzled k ^= (n&7)<<3
    __shared__ __align__(16) unsigned short sA[64 * 128];     // 16KB relu1, swizzled n ^= (e&7)<<3
    __shared__ __align__(16) float sPart[64 * 32];            // 8KB msg partials, rotated +5*(e&15)

    const int tid  = threadIdx.x;
    const int lane = tid & 63;
    const int wid  = tid >> 6;      // 0..7
    const int wc   = wid & 3;       // col chunk (128 cols)
    const int eg   = wid >> 2;      // edge half (32 edges)
    const int l15  = lane & 15;
    const int lg   = lane >> 4;     // 0..3
    const int key  = (l15 & 7) << 3;

    // ---- one-time: stage full W2T into LDS (swizzled), zero sPart ----
    #pragma unroll
    for (int j = 0; j < 16; ++j) {
        int flat = j * 512 + tid;               // uint4 index, < 8192
        int n = flat >> 4, k0 = (flat & 15) * 8;
        uint4 v = *reinterpret_cast<const uint4*>(&w2t[flat * 8]);
        *reinterpret_cast<uint4*>(&sB[n * 128 + (k0 ^ ((n & 7) << 3))]) = v;
    }
    {
        float4 z = {0.f, 0.f, 0.f, 0.f};
        *reinterpret_cast<float4*>(&sPart[tid * 4]) = z;
    }
    // hoisted invariants: layer-1 W1T fragment + biases for this lane
    bf16x8 w1f = *reinterpret_cast<const bf16x8*>(&w1t[(wid * 16 + l15) * 32 + lg * 8]);
    float4 b1q = *reinterpret_cast<const float4*>(&b1[wid * 16 + lg * 4]);
    __syncthreads();

    for (int tile = blockIdx.x; tile < N_TILES; tile += GRID_F) {
        const int e0 = tile * TILE_E;

        // early: src gather + x fragments (global, overlap with P1)
        int ea = eg * 32 + l15, eb = ea + 16;
        int sa = src[e0 + ea], sb = src[e0 + eb];
        float4 xva = *reinterpret_cast<const float4*>(&nf[sa * 16 + wc * 4]);
        float4 xvb = *reinterpret_cast<const float4*>(&nf[sb * 16 + wc * 4]);
        float xaa[4] = { xva.x, xva.y, xva.z, xva.w };
        float xab[4] = { xvb.x, xvb.y, xvb.z, xvb.w };

        // ---------- P1: layer-1 MFMA (wave wid owns n1-tile wid), all 4 e-tiles ----------
        #pragma unroll
        for (int et = 0; et < 4; ++et) {
            int e = et * 16 + l15;
            bf16x8 aef;
            if (lg < 2) {
                float4 f0 = *reinterpret_cast<const float4*>(&ef[(e0 + e) * 16 + lg * 8]);
                float4 f1 = *reinterpret_cast<const float4*>(&ef[(e0 + e) * 16 + lg * 8 + 4]);
                unsigned short t8[8] = { f32_bf16(f0.x), f32_bf16(f0.y), f32_bf16(f0.z), f32_bf16(f0.w),
                                         f32_bf16(f1.x), f32_bf16(f1.y), f32_bf16(f1.z), f32_bf16(f1.w) };
                aef = *reinterpret_cast<const bf16x8*>(t8);
            } else {
                aef = bf16x8(0);
            }
            f32x4 c = { b1q.x, b1q.y, b1q.z, b1q.w };
            c = __builtin_amdgcn_mfma_f32_16x16x32_bf16(w1f, aef, c, 0, 0, 0);
            // D[n1][e]: lane col = e, rows = wid*16 + lg*4 + r
            uint32_t u0 = (uint32_t)f32_bf16(fmaxf(c[0], 0.f)) | ((uint32_t)f32_bf16(fmaxf(c[1], 0.f)) << 16);
            uint32_t u1 = (uint32_t)f32_bf16(fmaxf(c[2], 0.f)) | ((uint32_t)f32_bf16(fmaxf(c[3], 0.f)) << 16);
            uint2 pk = { u0, u1 };
            *reinterpret_cast<uint2*>(&sA[e * 128 + ((wid * 16 + lg * 4) ^ key)]) = pk;
        }
        __syncthreads();

        // ---------- P2: layer-2 (B LDS-resident), fused msg partials ----------
        bf16x8 aF[2][4];
        #pragma unroll
        for (int et = 0; et < 2; ++et) {
            int e = eg * 32 + et * 16 + l15;
            #pragma unroll
            for (int kb = 0; kb < 4; ++kb)
                aF[et][kb] = *reinterpret_cast<const bf16x8*>(
                    &sA[e * 128 + ((kb * 32 + lg * 8) ^ key)]);
        }
        float msgv[2][8];
        #pragma unroll
        for (int et = 0; et < 2; ++et)
            #pragma unroll
            for (int q = 0; q < 8; ++q) msgv[et][q] = 0.f;

        #pragma unroll
        for (int f = 0; f < 8; ++f) {
            int n = wc * 128 + f * 16 + l15;
            bf16x8 bw[4];
            #pragma unroll
            for (int kb = 0; kb < 4; ++kb)
                bw[kb] = *reinterpret_cast<const bf16x8*>(
                    &sB[n * 128 + ((kb * 32 + lg * 8) ^ key)]);
            float4 b2q = *reinterpret_cast<const float4*>(&b2[wc * 128 + f * 16 + lg * 4]);
            f32x4 a0 = { b2q.x, b2q.y, b2q.z, b2q.w };
            f32x4 a1 = a0;
            #pragma unroll
            for (int kb = 0; kb < 4; ++kb) {
                a0 = __builtin_amdgcn_mfma_f32_16x16x32_bf16(bw[kb], aF[0][kb], a0, 0, 0, 0);
                a1 = __builtin_amdgcn_mfma_f32_16x16x32_bf16(bw[kb], aF[1][kb], a1, 0, 0, 0);
            }
            // i = wc*4 + (f>>1), h = (f&1)*16 + lg*4 + r
            const int s = (f & 1) * 4;
            #pragma unroll
            for (int r = 0; r < 4; ++r) {
                msgv[0][s + r] += xaa[f >> 1] * a0[r];
                msgv[1][s + r] += xab[f >> 1] * a1[r];
            }
        }
        // cross-wave i-reduction: rotated banks (5 coprime 32 -> <=2-way, free)
        #pragma unroll
        for (int et = 0; et < 2; ++et) {
            int e = eg * 32 + et * 16 + l15;
            int rot = 5 * l15;
            #pragma unroll
            for (int half = 0; half < 2; ++half)
                #pragma unroll
                for (int r = 0; r < 4; ++r) {
                    int hh = half * 16 + lg * 4 + r;
                    atomicAdd(&sPart[e * 32 + ((hh + rot) & 31)], msgv[et][half * 4 + r]);
                }
        }
        __syncthreads();

        // ---------- P3: read+rezero sPart (thread-exclusive slots), store msg ----------
        {
            int e = tid >> 3, h0 = (tid & 7) * 4;
            int rot = 5 * (e & 15);
            float v[4];
            #pragma unroll
            for (int j = 0; j < 4; ++j) {
                int idx = e * 32 + ((h0 + j + rot) & 31);
                v[j] = sPart[idx];
                sPart[idx] = 0.f;
            }
            float4 o = { v[0], v[1], v[2], v[3] };
            *reinterpret_cast<float4*>(&msg[(e0 + e) * 32 + h0]) = o;
        }
        __syncthreads();
    }
}

// ---- aggregate: h[n][hh] = relu(mean over slot edges of msg + conv_b) ----
__global__ __launch_bounds__(256) void aggregate_h(
    const float* __restrict__ msg, const int* __restrict__ cursor,
    const int* __restrict__ slots, const float* __restrict__ conv_b,
    float* __restrict__ h)
{
    int t = blockIdx.x * 256 + threadIdx.x;
    int n = t >> 5;
    if (n >= N_NODES) return;
    int hh = t & 31;
    int d = cursor[n];
    int dm = d < CAP ? d : CAP;
    const int* row = &slots[n * CAP];
    float s = 0.f;
    int j = 0;
    for (; j + 4 <= dm; j += 4) {
        int ee0 = row[j], ee1 = row[j + 1], ee2 = row[j + 2], ee3 = row[j + 3];
        float v0 = msg[ee0 * 32 + hh], v1 = msg[ee1 * 32 + hh];
        float v2 = msg[ee2 * 32 + hh], v3 = msg[ee3 * 32 + hh];
        s += (v0 + v1) + (v2 + v3);
    }
    for (; j < dm; ++j) s += msg[row[j] * 32 + hh];
    h[n * 32 + hh] = fmaxf(s / fmaxf((float)d, 1.f) + conv_b[hh], 0.f);
}

// ---- classifier: 32 edges per 256-thread block ----
__global__ __launch_bounds__(256) void classifier(
    const float* __restrict__ h, const float* __restrict__ ef,
    const int* __restrict__ src, const int* __restrict__ dst, const int* __restrict__ eidx,
    const float* __restrict__ w1, const float* __restrict__ b1,
    const float* __restrict__ w2, const float* __restrict__ b2, float* __restrict__ out)
{
    __shared__ float sIn[32][84];
    __shared__ float sW1[80 * 32];
    __shared__ float sHid[32][36];
    __shared__ int   sE[32 * 3];
    int tid = threadIdx.x;
    int eb  = blockIdx.x * 32;

    for (int i = tid; i < 640; i += 256)
        *reinterpret_cast<float4*>(&sW1[i * 4]) = *reinterpret_cast<const float4*>(&w1[i * 4]);
    if (tid < 32) {
        int ei = eidx[eb + tid];
        sE[tid * 3 + 0] = ei;
        sE[tid * 3 + 1] = src[ei];
        sE[tid * 3 + 2] = dst[ei];
    }
    __syncthreads();
    {
        int e = tid >> 3, l8 = tid & 7;
        int ei = sE[e * 3 + 0], sn = sE[e * 3 + 1], dn = sE[e * 3 + 2];
        #pragma unroll
        for (int j = 0; j < 10; ++j) {
            int c = l8 + j * 8;
            float v;
            if (c < 32)      v = h[sn * 32 + c];
            else if (c < 64) v = h[dn * 32 + (c - 32)];
            else             v = ef[ei * 16 + (c - 64)];
            sIn[e][c] = v;
        }
    }
    __syncthreads();
    {
        int e = tid >> 3, j0 = (tid & 7) * 4;
        float4 acc = *reinterpret_cast<const float4*>(&b1[j0]);
        #pragma unroll 8
        for (int k = 0; k < 80; ++k) {
            float x = sIn[e][k];
            float4 wv = *reinterpret_cast<const float4*>(&sW1[k * 32 + j0]);
            acc.x += x * wv.x; acc.y += x * wv.y; acc.z += x * wv.z; acc.w += x * wv.w;
        }
        sHid[e][j0 + 0] = fmaxf(acc.x, 0.f);
        sHid[e][j0 + 1] = fmaxf(acc.y, 0.f);
        sHid[e][j0 + 2] = fmaxf(acc.z, 0.f);
        sHid[e][j0 + 3] = fmaxf(acc.w, 0.f);
    }
    __syncthreads();
    if (tid < 64) {
        int e = tid >> 1, o = tid & 1;
        float acc = b2[o];
        #pragma unroll
        for (int j = 0; j < 32; ++j) acc += sHid[e][j] * w2[j * 2 + o];
        out[(eb + e) * 2 + o] = acc;
    }
}

extern "C" void kernel_launch(void* const* d_in, const int* in_sizes, int n_in,
                              void* d_out, int out_size, void* d_ws, size_t ws_size,
                              hipStream_t stream) {
    const float* nf     = (const float*)d_in[0];
    const float* ef     = (const float*)d_in[1];
    const int*   src    = (const int*)d_in[2];
    const int*   dst    = (const int*)d_in[3];
    const int*   eidx   = (const int*)d_in[4];
    const float* en_w1  = (const float*)d_in[5];
    const float* en_b1  = (const float*)d_in[6];
    const float* en_w2  = (const float*)d_in[7];
    const float* en_b2  = (const float*)d_in[8];
    const float* conv_b = (const float*)d_in[9];
    const float* cls_w1 = (const float*)d_in[10];
    const float* cls_b1 = (const float*)d_in[11];
    const float* cls_w2 = (const float*)d_in[12];
    const float* cls_b2 = (const float*)d_in[13];
    float* out = (float*)d_out;

    char* ws = (char*)d_ws;
    unsigned short* w2t    = (unsigned short*)(ws);                 // 131,072 B
    unsigned short* w1t    = (unsigned short*)(ws + 131072);        //   8,192 B
    int*            cursor = (int*)(ws + 139264);                   // 200,000 B
    int*            slots  = (int*)(ws + 339264);                   // 8,000,000 B (50K * 40 * 4)
    float*          msgb   = (float*)(ws + 8339264);                // 51,200,000 B
    float*          h      = (float*)(ws + 59539264);               // 6,400,000 B  (end ~65.9 MB)

    zero_int<<<(N_NODES + 255) / 256, 256, 0, stream>>>(cursor, N_NODES);
    prep_weights<<<(NOUT * K1 + 4096) / 256, 256, 0, stream>>>(en_w2, en_w1, w2t, w1t);
    build_slots<<<(N_EDGES + 255) / 256, 256, 0, stream>>>(dst, cursor, slots);
    fused_msg<<<GRID_F, 512, 0, stream>>>(nf, ef, src, w1t, en_b1, w2t, en_b2, msgb);
    aggregate_h<<<(N_NODES * HIDDEN + 255) / 256, 256, 0, stream>>>(msgb, cursor, slots, conv_b, h);
    classifier<<<N_CLS / 32, 256, 0, stream>>>(h, ef, src, dst, eidx, cls_w1, cls_b1, cls_w2, cls_b2, out);
}